// Round 10
// baseline (110.010 us; speedup 1.0000x reference)
//
#include <hip/hip_runtime.h>

#define CC 192
#define NN 16384
#define QSD 264   // dwords per 4-channel stripe in Xf (256 data + 8 pad)
#define QST 200   // kq SsT stride (elems)

typedef unsigned short u16;
typedef __attribute__((ext_vector_type(4))) float f32x4;
typedef __attribute__((ext_vector_type(8))) __bf16 bf16x8;
typedef __attribute__((ext_vector_type(8))) u16 u16x8;

union FragU { u16x8 u; bf16x8 b; };

__device__ __forceinline__ u16 f2bf(float f) {
  union { float f; unsigned u; } x; x.f = f;
  return (u16)((x.u + 0x7FFFu + ((x.u >> 16) & 1u)) >> 16);  // RNE
}
__device__ __forceinline__ float bf2f(u16 h) {
  union { unsigned u; float f; } x; x.u = ((unsigned)h) << 16;
  return x.f;
}

// Direct global->LDS DMA, 16B per lane, no VGPR round-trip.
__device__ __forceinline__ void gl_lds16(const float* g, float* l) {
  __builtin_amdgcn_global_load_lds(
      (const __attribute__((address_space(1))) void*)g,
      (__attribute__((address_space(3))) void*)l, 16, 0, 0);
}

// Stage one 192ch x 64tok fp32 tile into Xf stripes via DMA.
// Stripe q holds channels 4q..4q+3: Xf[q*QSD + ch_w*64 + tok].
// Lane L of instruction q: global ch = 4q + (L>>4), toks (L&15)*4.. (16B) ->
// LDS dest base + L*16 lands at exactly [ch_w][tok] (linear within stripe).
__device__ __forceinline__ void stage_dma(const float* __restrict__ xb, int t0,
                                          int lane, int wv, float* Xf) {
#pragma unroll
  for (int i = 0; i < 12; ++i) {
    const int q = wv * 12 + i;
    const float* gsrc = xb + (size_t)(q * 4 + (lane >> 4)) * NN + t0 + (lane & 15) * 4;
    gl_lds16(gsrc, &Xf[q * QSD]);
  }
}

// Build B-frag (ks, nt) from fp32 stripes: lane (lg,lc) needs ch = ks*32+lg*8+j,
// tok = nt*16+lc. Bank pattern: 2 lanes/bank -> conflict-free cost.
__device__ __forceinline__ u16x8 bfrag(const float* Xf, int ks, int nt, int lg, int lc) {
  u16x8 f;
#pragma unroll
  for (int j = 0; j < 8; ++j) {
    const int ch = ks * 32 + lg * 8 + j;
    f[j] = f2bf(Xf[(ch >> 2) * QSD + (ch & 3) * 64 + nt * 16 + lc]);
  }
  return f;
}

// K/V projection: DMA-staged fp32 tile, 6 MFMA k-steps, bias(+exp) epilogue.
// z=0: Sexp = exp(Wk@k+bk); z=1: Vbuf = Wv@v+bv  (bf16 [b][e][n]).
__global__ __launch_bounds__(256, 2)
void kproj(const float* __restrict__ k, const float* __restrict__ v,
           const u16* __restrict__ Wb, const float* __restrict__ bk,
           const float* __restrict__ bv, u16* __restrict__ Sexp,
           u16* __restrict__ Vbuf)
{
  __shared__ __align__(16) float Xf[48 * QSD];   // 50.7 KB -> 3 blocks/CU
  const int b = blockIdx.y, pj = blockIdx.z;
  const int t0 = blockIdx.x * 64;
  const int tid = threadIdx.x;
  const int lane = tid & 63, wv = tid >> 6;
  const int lg = lane >> 4, lc = lane & 15;
  const int e0 = wv * 48;

  const float* xb = (pj ? v : k) + (size_t)b * CC * NN;
  const u16* Wp = Wb + (pj ? 2 : 1) * 36864;
  const float* bias = pj ? bv : bk;
  u16* outp = pj ? Vbuf : Sexp;

  // ---- DMA stage (no VGPRs; all 12 loads stay in flight until the barrier) ----
  stage_dma(xb, t0, lane, wv, Xf);

  // ---- W A-frags (L2-hot) ----
  FragU wfr[6][3];
#pragma unroll
  for (int ks = 0; ks < 6; ++ks)
#pragma unroll
    for (int et = 0; et < 3; ++et)
      wfr[ks][et].u = *reinterpret_cast<const u16x8*>(
          &Wp[(e0 + et * 16 + lc) * 192 + ks * 32 + lg * 8]);

  __syncthreads();   // drains DMA (vmcnt) + hands off LDS

  // ---- 6 MFMA k-steps; B-frags built from fp32 LDS with on-the-fly cvt ----
  f32x4 acc[3][4];
#pragma unroll
  for (int et = 0; et < 3; ++et)
#pragma unroll
    for (int nt = 0; nt < 4; ++nt) acc[et][nt] = f32x4{0.f, 0.f, 0.f, 0.f};

#pragma unroll
  for (int ks = 0; ks < 6; ++ks) {
    FragU bb[4];
#pragma unroll
    for (int nt = 0; nt < 4; ++nt) bb[nt].u = bfrag(Xf, ks, nt, lg, lc);
#pragma unroll
    for (int et = 0; et < 3; ++et)
#pragma unroll
      for (int nt = 0; nt < 4; ++nt)
        acc[et][nt] = __builtin_amdgcn_mfma_f32_16x16x32_bf16(wfr[ks][et].b, bb[nt].b,
                                                             acc[et][nt], 0, 0, 0);
  }

  // ---- epilogue: bias (+exp for K), bf16 stores ----
#pragma unroll
  for (int et = 0; et < 3; ++et)
#pragma unroll
    for (int r = 0; r < 4; ++r) {
      const int e = e0 + et * 16 + lg * 4 + r;
      const float bb = bias[e];
      u16* orow = outp + (size_t)(b * 192 + e) * NN + t0;
#pragma unroll
      for (int nt = 0; nt < 4; ++nt) {
        float val = acc[et][nt][r] + bb;
        if (!pj) val = __expf(val);        // |kp| small; no max-sub needed
        orow[nt * 16 + lc] = f2bf(val);
      }
    }
}

// ctx partials: block = (128-token slab, batch); 8 waves, wave = head. No LDS.
__global__ __launch_bounds__(512, 2)
void kctx(const u16* __restrict__ Sexp, const u16* __restrict__ Vbuf,
          float* __restrict__ part)
{
  const int b = blockIdx.y, slab = blockIdx.x;
  const int tid = threadIdx.x;
  const int h = tid >> 6;
  const int lg = (tid >> 4) & 3, lc = tid & 15;
  const int n0 = slab * 128;
  const size_t basee = (size_t)b * 192 * NN;

  f32x4 cacc[2][2];
#pragma unroll
  for (int mt = 0; mt < 2; ++mt)
#pragma unroll
    for (int nt = 0; nt < 2; ++nt) cacc[mt][nt] = f32x4{0.f, 0.f, 0.f, 0.f};

#pragma unroll
  for (int ks = 0; ks < 4; ++ks) {
    const int tok = n0 + ks * 32 + lg * 8;
    FragU av[2], bs[2];
#pragma unroll
    for (int mt = 0; mt < 2; ++mt) {
      int row = h * 24 + mt * 16 + lc;   // rows >= h*24+24 feed masked outputs
      if (row > 191) row = 191;
      av[mt].u = *reinterpret_cast<const u16x8*>(&Vbuf[basee + (size_t)row * NN + tok]);
      bs[mt].u = *reinterpret_cast<const u16x8*>(&Sexp[basee + (size_t)row * NN + tok]);
    }
#pragma unroll
    for (int mt = 0; mt < 2; ++mt)
#pragma unroll
      for (int nt = 0; nt < 2; ++nt)
        cacc[mt][nt] = __builtin_amdgcn_mfma_f32_16x16x32_bf16(
            av[mt].b, bs[nt].b, cacc[mt][nt], 0, 0, 0);
  }

  float* pp = part + (((size_t)(b * 128 + slab)) * 8 + h) * 576;
#pragma unroll
  for (int mt = 0; mt < 2; ++mt)
#pragma unroll
    for (int nt = 0; nt < 2; ++nt)
#pragma unroll
      for (int r = 0; r < 4; ++r) {
        const int dv = mt * 16 + lg * 4 + r;
        const int d = nt * 16 + lc;
        if (dv < 24 && d < 24) pp[dv * 24 + d] = cacc[mt][nt][r];
      }
}

// ksum[row] = sum_n Sexp[row][n]
__global__ __launch_bounds__(256, 2)
void krow(const u16* __restrict__ Sexp, float* __restrict__ ksum)
{
  __shared__ float red[4];
  const int row = blockIdx.x;
  const int tid = threadIdx.x;
  const u16* p = Sexp + (size_t)row * NN;
  float s = 0.f;
#pragma unroll
  for (int i = 0; i < 8; ++i) {
    u16x8 vv = *reinterpret_cast<const u16x8*>(&p[(i * 256 + tid) * 8]);
#pragma unroll
    for (int j = 0; j < 8; ++j) s += bf2f(vv[j]);
  }
#pragma unroll
  for (int off = 1; off < 64; off <<= 1) s += __shfl_xor(s, off);
  if ((tid & 63) == 0) red[tid >> 6] = s;
  __syncthreads();
  if (tid == 0) ksum[row] = red[0] + red[1] + red[2] + red[3];
}

// Reduce 128 slab partials + normalize
__global__ void kr2(const float* __restrict__ part, const float* __restrict__ ksum,
                    float* __restrict__ ctx)
{
  const int idx = blockIdx.x * 256 + threadIdx.x;
  if (idx >= 4608) return;
  const int b = blockIdx.y;
  const int h = idx / 576, rem = idx % 576;
  const int d = rem % 24;
  float s = 0.f;
  const float* pp = part + (size_t)b * 128 * 4608 + idx;
#pragma unroll 8
  for (int j = 0; j < 128; ++j) s += pp[(size_t)j * 4608];
  ctx[(size_t)b * 4608 + idx] = s / ksum[b * 192 + h * 24 + d];
}

// Meff[b][o][h*24+d] = sum_dv Wo[o][h*24+dv] * ctx[b][h][dv*24+d]
__global__ void km(const float* __restrict__ Wo, const float* __restrict__ ctx,
                   u16* __restrict__ Meff)
{
  const int o = blockIdx.x, b = blockIdx.y, j = threadIdx.x;
  const int h = j / 24, d = j % 24;
  const float* Wrow = Wo + o * 192 + h * 24;
  const float* crow = ctx + (size_t)b * 4608 + h * 576 + d;
  float acc = 0.f;
#pragma unroll
  for (int dv = 0; dv < 24; ++dv) acc += Wrow[dv] * crow[dv * 24];
  Meff[(b * 192 + o) * 192 + j] = f2bf(acc);
}

// Q kernel: DMA-staged q tile -> q-proj GEMM -> SsT -> softmax -> Meff GEMM -> out.
__global__ __launch_bounds__(256, 2)
void kq(const float* __restrict__ q, const u16* __restrict__ Wb,
        const float* __restrict__ bq, const u16* __restrict__ Meff,
        const float* __restrict__ bo, float* __restrict__ out)
{
  __shared__ __align__(16) float Xf[48 * QSD];   // 50.7 KB
  __shared__ __align__(16) u16 SsT[64][QST];     // 25.6 KB -> 2 blocks/CU

  const int b = blockIdx.y;
  const int t0 = blockIdx.x * 64;
  const int tid = threadIdx.x;
  const int lane = tid & 63, wv = tid >> 6;
  const int lg = lane >> 4, lc = lane & 15;
  const int e0 = wv * 48;
  const u16* Mb = Meff + b * 36864;

  stage_dma(q + (size_t)b * CC * NN, t0, lane, wv, Xf);

  FragU wfr[6][3];
#pragma unroll
  for (int ks = 0; ks < 6; ++ks)
#pragma unroll
    for (int et = 0; et < 3; ++et)
      wfr[ks][et].u = *reinterpret_cast<const u16x8*>(
          &Wb[(e0 + et * 16 + lc) * 192 + ks * 32 + lg * 8]);

  __syncthreads();

  // ---- q-projection GEMM ----
  f32x4 acc[3][4];
#pragma unroll
  for (int et = 0; et < 3; ++et)
#pragma unroll
    for (int nt = 0; nt < 4; ++nt) acc[et][nt] = f32x4{0.f, 0.f, 0.f, 0.f};
#pragma unroll
  for (int ks = 0; ks < 6; ++ks) {
    FragU bb[4];
#pragma unroll
    for (int nt = 0; nt < 4; ++nt) bb[nt].u = bfrag(Xf, ks, nt, lg, lc);
#pragma unroll
    for (int et = 0; et < 3; ++et)
#pragma unroll
      for (int nt = 0; nt < 4; ++nt)
        acc[et][nt] = __builtin_amdgcn_mfma_f32_16x16x32_bf16(wfr[ks][et].b, bb[nt].b,
                                                             acc[et][nt], 0, 0, 0);
  }

  // ---- write SsT[n][e] (transposed) + bias ----
#pragma unroll
  for (int et = 0; et < 3; ++et)
#pragma unroll
    for (int r = 0; r < 4; ++r) {
      const int e = e0 + et * 16 + lg * 4 + r;
      const float bias = bq[e];
#pragma unroll
      for (int nt = 0; nt < 4; ++nt)
        SsT[nt * 16 + lc][e] = f2bf(acc[et][nt][r] + bias);
    }
  __syncthreads();

  // ---- softmax over d (24) per (token, head), in-place ----
#pragma unroll
  for (int ii = 0; ii < 2; ++ii) {
    const int item = ii * 256 + tid;
    const int n = item & 63, h = item >> 6;
    u16* rowp = &SsT[n][h * 24];
    float vals[24];
    float m = -1e30f;
#pragma unroll
    for (int d = 0; d < 24; ++d) {
      vals[d] = bf2f(rowp[d]);
      m = fmaxf(m, vals[d]);
    }
    float s = 0.f;
#pragma unroll
    for (int d = 0; d < 24; ++d) { vals[d] = __expf(vals[d] - m); s += vals[d]; }
    const float inv = 1.f / s;
#pragma unroll
    for (int d = 0; d < 24; ++d) rowp[d] = f2bf(vals[d] * inv);
  }
  __syncthreads();

  // ---- output GEMM: Meff (192x192) @ SsT^T ----
#pragma unroll
  for (int et = 0; et < 3; ++et)
#pragma unroll
    for (int nt = 0; nt < 4; ++nt) acc[et][nt] = f32x4{0.f, 0.f, 0.f, 0.f};
#pragma unroll
  for (int ks = 0; ks < 6; ++ks) {
    FragU a[3], bb[4];
#pragma unroll
    for (int et = 0; et < 3; ++et)
      a[et].u = *reinterpret_cast<const u16x8*>(
          &Mb[(e0 + et * 16 + lc) * 192 + ks * 32 + lg * 8]);
#pragma unroll
    for (int nt = 0; nt < 4; ++nt)
      bb[nt].u = *reinterpret_cast<const u16x8*>(&SsT[nt * 16 + lc][ks * 32 + lg * 8]);
#pragma unroll
    for (int et = 0; et < 3; ++et)
#pragma unroll
      for (int nt = 0; nt < 4; ++nt)
        acc[et][nt] = __builtin_amdgcn_mfma_f32_16x16x32_bf16(a[et].b, bb[nt].b,
                                                             acc[et][nt], 0, 0, 0);
  }

#pragma unroll
  for (int et = 0; et < 3; ++et)
#pragma unroll
    for (int r = 0; r < 4; ++r) {
      const int row = e0 + et * 16 + lg * 4 + r;
      const float bias = bo[row];
#pragma unroll
      for (int nt = 0; nt < 4; ++nt)
        out[(size_t)(b * 192 + row) * NN + t0 + nt * 16 + lc] = acc[et][nt][r] + bias;
    }
}

// Convert Wq/Wk/Wv to bf16 (packed [3][192][192]).
__global__ void kz(const float* __restrict__ Wq, const float* __restrict__ Wk,
                   const float* __restrict__ Wv, u16* __restrict__ Wb)
{
  const int i = blockIdx.x * 256 + threadIdx.x;
  if (i < 110592) {
    const float* src = (i < 36864) ? Wq : (i < 73728) ? Wk : Wv;
    Wb[i] = f2bf(src[i % 36864]);
  }
}

extern "C" void kernel_launch(void* const* d_in, const int* in_sizes, int n_in,
                              void* d_out, int out_size, void* d_ws, size_t ws_size,
                              hipStream_t stream)
{
  const float* q  = (const float*)d_in[0];
  const float* k  = (const float*)d_in[1];
  const float* v  = (const float*)d_in[2];
  const float* Wq = (const float*)d_in[3];
  const float* bq = (const float*)d_in[4];
  const float* Wk = (const float*)d_in[5];
  const float* bk = (const float*)d_in[6];
  const float* Wv = (const float*)d_in[7];
  const float* bv = (const float*)d_in[8];
  const float* Wo = (const float*)d_in[9];
  const float* bo = (const float*)d_in[10];
  float* out = (float*)d_out;

  // workspace carve (256B-aligned); total ~60.4 MB
  char* w = (char*)d_ws;
  u16*   Wb   = (u16*)(w);                     // 221184 B
  u16*   Sexp = (u16*)(w + 221184);            // 25165824 B : [4][192][16384] bf16
  u16*   Vbuf = (u16*)(w + 25387008);          // 25165824 B
  float* part = (float*)(w + 50552832);        // 9437184 B : [4][128][8][576]
  float* ksum = (float*)(w + 59990016);        // 3072 B
  float* ctx  = (float*)(w + 59993088);        // 73728 B
  u16*   Meff = (u16*)(w + 60066816);          // 294912 B

  hipLaunchKernelGGL(kz, dim3(432), dim3(256), 0, stream, Wq, Wk, Wv, Wb);
  hipLaunchKernelGGL(kproj, dim3(256, 4, 2), dim3(256), 0, stream,
                     k, v, Wb, bk, bv, Sexp, Vbuf);
  hipLaunchKernelGGL(krow, dim3(768), dim3(256), 0, stream, Sexp, ksum);
  hipLaunchKernelGGL(kctx, dim3(128, 4), dim3(512), 0, stream, Sexp, Vbuf, part);
  hipLaunchKernelGGL(kr2, dim3(18, 4), dim3(256), 0, stream, part, ksum, ctx);
  hipLaunchKernelGGL(km, dim3(192, 4), dim3(192), 0, stream, Wo, ctx, Meff);
  hipLaunchKernelGGL(kq, dim3(256, 4), dim3(256), 0, stream, q, Wb, bq, Meff, bo, out);
}